// Round 11
// baseline (780.635 us; speedup 1.0000x reference)
//
#include <hip/hip_runtime.h>
#include <cstddef>

typedef _Float16 f16;
typedef f16 f16x4 __attribute__((ext_vector_type(4)));
typedef f16 f16x8 __attribute__((ext_vector_type(8)));
typedef float f32x4 __attribute__((ext_vector_type(4)));

// async global->LDS, 16B per lane. LDS dest = uniform base + lane*16 (HW);
// global src is per-lane.
__device__ inline void gld_lds16(const f16* g, f16* l) {
    __builtin_amdgcn_global_load_lds(
        (const __attribute__((address_space(1))) void*)g,
        (__attribute__((address_space(3))) void*)l, 16, 0, 0);
}

// ---------------------------------------------------------------------------
// MFMA submanifold conv, A-direct / B-in-LDS.
//  - REGISTER RULE (R10 lesson): gfx950 unified VGPR+AGPR file; occupancy
//    quantum halves above 128 TOTAL regs. arch(va/vl/addr) + acc AGPRs must
//    stay <=128 for 4 waves/SIMD (2 co-resident 8-wave blocks). R10's
//    NTB=3+MROW=2 hit 84+64=148 -> 2 waves/SIMD -> 23% occ -> exposed
//    barriers. NTB=2 keeps acc at 32.
//  - MROW=2: each B chunk pair read from LDS feeds 2x the MFMAs (LDS-read
//    throughput was ~80% of conv2 at MROW=1).
//  - A fragments: per-lane 16B loads from pre-split f16 planes (hi at base,
//    lo at +in_plane). Row N = zeros. CS col-split multiplies A-gather
//    traffic; XCD swizzle keeps cs-twins on one XCD so re-reads hit L2.
//  - TERMS=2: Markidis f16 split (hi + lo*2^12), 3 MFMAs/pair -> ~fp32
//    accuracy (mask-threshold chain). TERMS=1: plain f16 (points chain).
//  - BMODE 0: whole weight set in LDS, no k barriers (PIPEA reg-dbuf A).
//    BMODE 1: per-k LDS double-buffer, 1 barrier/k (A(k+1) issued pre-drain).
//    BMODE 2: per-k single buffer, 2 barriers/k (50KB k-slices).
//  - Bijective XCD-chunk swizzle (nwg % 8 == 0).
// ---------------------------------------------------------------------------
template<int C, int NTB, int CS, int WCO, int TERMS, int WAVES, int BMODE,
         int OUTM, int PIPEA, int MROW>
__global__ __launch_bounds__(WAVES * 64)
void conv_mfma(const f16* __restrict__ fin, size_t in_plane,
               const int* __restrict__ nbr,
               const f16* __restrict__ Wb,
               void* __restrict__ outv, int ostride, int ooff, size_t out_plane,
               int CO_real, int N, int Nstore, int tilesPad)
{
    constexpr int KK   = C / 32;
    constexpr int KKL  = (TERMS == 2) ? KK : 1;
    constexpr int NTBT = WCO * NTB;             // col tiles per (k, cs)
    constexpr int CH   = KK * NTBT * TERMS;     // 1KB fragment chunks per (k,cs)
    constexpr int WROW = WAVES / WCO;
    constexpr int ROWS = WROW * MROW * 16;
    constexpr int BUFS = (BMODE == 0) ? 27 : ((BMODE == 1) ? 2 : 1);
    static_assert(!(BMODE == 0 && MROW != 1), "BMODE0 path is MROW=1");
    __shared__ f16 sB[BUFS * CH * 512];

    const int lane = threadIdx.x & 63;
    const int w    = threadIdx.x >> 6;
    const int wco  = w % WCO;
    const int wrow = w / WCO;
    int gid = blockIdx.x;
    { const int q = (tilesPad * CS) >> 3; gid = (gid & 7) * q + (gid >> 3); }
    const int tile = gid / CS;
    const int cs   = gid - tile * CS;
    const int n0   = tile * ROWS;
    const int NZ   = N;                          // zero row
    const int h8   = (lane >> 4) * 8;

    int  site[MROW];
    bool sv[MROW];
#pragma unroll
    for (int r = 0; r < MROW; ++r) {
        site[r] = n0 + (wrow * MROW + r) * 16 + (lane & 15);
        sv[r]   = site[r] < N;
    }

    auto nbrIdx = [&](int r, int k) -> int {
        int v = sv[r] ? nbr[(size_t)site[r] * 27 + k] : -1;
        return (v < 0) ? NZ : v;
    };

    auto stageK = [&](int k, int buf) {
        const f16* src = Wb + ((size_t)(k * CS + cs) * CH) * 512 + lane * 8;
        f16* dst = &sB[(size_t)buf * CH * 512];
#pragma unroll
        for (int c = w; c < CH; c += WAVES)
            gld_lds16(src + (size_t)c * 512, dst + (size_t)c * 512);
    };

    f32x4 acc[MROW * NTB], acc2[MROW * NTB];
#pragma unroll
    for (int i = 0; i < MROW * NTB; ++i) {
        acc[i]  = (f32x4){0.f, 0.f, 0.f, 0.f};
        acc2[i] = (f32x4){0.f, 0.f, 0.f, 0.f};
    }

    f16x8 va[MROW * KK], vl[MROW * KKL];
    f16x8 vaB[(BMODE == 0 && PIPEA) ? KK : 1], vlB[(BMODE == 0 && PIPEA) ? KKL : 1];

    auto loadA = [&](int idx, f16x8* pva, f16x8* pvl) {
        const f16* arow = fin + (size_t)idx * C + h8;
#pragma unroll
        for (int kk = 0; kk < KK; ++kk) {
            pva[kk] = *(const f16x8*)(arow + kk * 32);
            if constexpr (TERMS == 2)
                pvl[kk] = *(const f16x8*)(arow + in_plane + kk * 32);
        }
    };

    auto mfmaPhase = [&](const f16x8* pva, const f16x8* pvl, int kbuf) {
        const f16* sBc = &sB[(size_t)kbuf * CH * 512] + lane * 8;
#pragma unroll
        for (int kk = 0; kk < KK; ++kk) {
#pragma unroll
            for (int nt = 0; nt < NTB; ++nt) {
                const f16* bp = sBc + (size_t)((kk * NTBT + wco * NTB + nt) * TERMS) * 512;
                const f16x8 bh = *(const f16x8*)bp;
                if constexpr (TERMS == 2) {
                    const f16x8 bl = *(const f16x8*)(bp + 512);
#pragma unroll
                    for (int r = 0; r < MROW; ++r) {
                        acc[r * NTB + nt]  = __builtin_amdgcn_mfma_f32_16x16x32_f16(
                            pva[r * KK + kk], bh, acc[r * NTB + nt], 0, 0, 0);
                        acc2[r * NTB + nt] = __builtin_amdgcn_mfma_f32_16x16x32_f16(
                            pva[r * KK + kk], bl, acc2[r * NTB + nt], 0, 0, 0);
                        acc2[r * NTB + nt] = __builtin_amdgcn_mfma_f32_16x16x32_f16(
                            pvl[r * KK + kk], bh, acc2[r * NTB + nt], 0, 0, 0);
                    }
                } else {
#pragma unroll
                    for (int r = 0; r < MROW; ++r)
                        acc[r * NTB + nt] = __builtin_amdgcn_mfma_f32_16x16x32_f16(
                            pva[r * KK + kk], bh, acc[r * NTB + nt], 0, 0, 0);
                }
            }
        }
    };

    if constexpr (BMODE == 1) {
        // ---- per-k dbuf; 1 barrier/k; A(k+1) issued pre-drain ----
        int idxN[MROW];
#pragma unroll
        for (int r = 0; r < MROW; ++r)
            loadA(nbrIdx(r, 0), &va[r * KK], &vl[r * KKL]);
        stageK(0, 0);
#pragma unroll
        for (int r = 0; r < MROW; ++r) idxN[r] = nbrIdx(r, 1);
        __syncthreads();                       // drains A(0) + B(0)

        for (int k = 0; k < 27; ++k) {
            if (k + 1 < 27) stageK(k + 1, (k + 1) & 1);
            mfmaPhase(va, vl, k & 1);          // A(k), B(k) complete
            if (k + 1 < 27) {
#pragma unroll
                for (int r = 0; r < MROW; ++r)
                    loadA(idxN[r], &va[r * KK], &vl[r * KKL]);
#pragma unroll
                for (int r = 0; r < MROW; ++r)
                    idxN[r] = (k + 2 < 27) ? nbrIdx(r, k + 2) : NZ;
                __syncthreads();               // drains A(k+1) + B(k+1)
            }
        }
    } else if constexpr (BMODE == 2) {
        // ---- per-k single buffer; 2 barriers/k (covered by co-res block) ----
        int idxN[MROW];
#pragma unroll
        for (int r = 0; r < MROW; ++r)
            loadA(nbrIdx(r, 0), &va[r * KK], &vl[r * KKL]);
#pragma unroll
        for (int r = 0; r < MROW; ++r) idxN[r] = nbrIdx(r, 1);

        for (int k = 0; k < 27; ++k) {
            stageK(k, 0);                      // prev reads done (barrier below)
            __syncthreads();                   // drains stage(k) + A(k)
            mfmaPhase(va, vl, 0);
            if (k + 1 < 27) {
#pragma unroll
                for (int r = 0; r < MROW; ++r)
                    loadA(idxN[r], &va[r * KK], &vl[r * KKL]);
#pragma unroll
                for (int r = 0; r < MROW; ++r)
                    idxN[r] = (k + 2 < 27) ? nbrIdx(r, k + 2) : NZ;
                __syncthreads();               // B(k) reads done before restage
            }
        }
    } else {
        // ---- whole-B resident, no k-loop barriers; PIPEA A reg-dbuf ----
#pragma unroll
        for (int c = w; c < 27 * CH; c += WAVES)
            gld_lds16(Wb + (size_t)c * 512 + lane * 8, &sB[(size_t)c * 512]);
        int idxC = nbrIdx(0, 0);
        loadA(idxC, va, vl);
        int idxN = nbrIdx(0, 1);
        __syncthreads();

        if constexpr (PIPEA) {
            auto body = [&](int k, f16x8* vac, f16x8* vlc, f16x8* van, f16x8* vln) {
                if (k >= 27) return;
                if (k + 1 < 27) {
                    loadA(idxN, van, vln);
                    idxN = (k + 2 < 27) ? nbrIdx(0, k + 2) : NZ;
                }
                mfmaPhase(vac, vlc, k);
            };
            for (int k2 = 0; k2 < 27; k2 += 2) {
                body(k2, va, vl, vaB, vlB);
                body(k2 + 1, vaB, vlB, va, vl);
            }
        } else {
            for (int k = 0; k < 27; ++k) {
                mfmaPhase(va, vl, k);
                if (k + 1 < 27) {
                    loadA(idxN, va, vl);
                    idxN = (k + 2 < 27) ? nbrIdx(0, k + 2) : NZ;
                }
            }
        }
    }

    // ---- epilogue: D col=lane&15, row=(lane>>4)*4+j ----
    const int colg = lane & 15;
    const int rg   = lane >> 4;
#pragma unroll
    for (int r = 0; r < MROW; ++r) {
#pragma unroll
        for (int nt = 0; nt < NTB; ++nt) {
#pragma unroll
            for (int j = 0; j < 4; ++j) {
                float v = acc[r * NTB + nt][j];
                if constexpr (TERMS == 2) v += acc2[r * NTB + nt][j] * (1.f / 4096.f);
                const int n  = n0 + (wrow * MROW + r) * 16 + rg * 4 + j;
                const int co = ((cs * WCO + wco) * NTB + nt) * 16 + colg;
                if (n < Nstore && co < CO_real) {
                    if constexpr (OUTM == 0) {
                        ((float*)outv)[(size_t)n * ostride + ooff + co] = v;
                    } else if constexpr (OUTM == 1) {
                        ((f16*)outv)[(size_t)n * ostride + co] = (f16)v;
                    } else {
                        f16* o = (f16*)outv;
                        const f16 h = (f16)v;
                        o[(size_t)n * ostride + co] = h;
                        o[out_plane + (size_t)n * ostride + co] = (f16)((v - (float)h) * 4096.f);
                    }
                }
            }
        }
    }
}

// ---------------------------------------------------------------------------
// P-factorized score: P[k][R][c] = f[R] @ Ws[k][:,c] as ONE dense GEMM
// f[N x C] @ Wflat[C x 54->64] (no gather). P is f32 [27][N][2].
// ---------------------------------------------------------------------------
template<int C>
__global__ __launch_bounds__(256)
void pgemm_score(const f16* __restrict__ fin, size_t plane,
                 const f16* __restrict__ Wb,   // (C/32)*4*2 chunks
                 float* __restrict__ P, int N)
{
    constexpr int KK = C / 32;
    constexpr int CH = KK * 4 * 2;
    __shared__ f16 sB[CH * 512];

    const int tid  = threadIdx.x;
    const int lane = tid & 63;
    const int w    = tid >> 6;

    const int n0 = blockIdx.x * 64;
    int site = n0 + w * 16 + (lane & 15);
    if (site > N) site = N;                 // zero row for tails
    const int h8 = (lane >> 4) * 8;

    f16x8 va[KK], vl[KK];
    const f16* arow = fin + (size_t)site * C + h8;
#pragma unroll
    for (int kk = 0; kk < KK; ++kk) {
        va[kk] = *(const f16x8*)(arow + kk * 32);
        vl[kk] = *(const f16x8*)(arow + plane + kk * 32);
    }
    for (int c = w; c < CH; c += 4)
        gld_lds16(Wb + (size_t)c * 512 + lane * 8, &sB[(size_t)c * 512]);

    f32x4 acc[4], acc2[4];
#pragma unroll
    for (int nt = 0; nt < 4; ++nt) {
        acc[nt]  = (f32x4){0.f, 0.f, 0.f, 0.f};
        acc2[nt] = (f32x4){0.f, 0.f, 0.f, 0.f};
    }
    __syncthreads();

#pragma unroll
    for (int kk = 0; kk < KK; ++kk) {
#pragma unroll
        for (int nt = 0; nt < 4; ++nt) {
            const f16* bp = &sB[(size_t)((kk * 4 + nt) * 2) * 512] + lane * 8;
            const f16x8 bh = *(const f16x8*)bp;
            const f16x8 bl = *(const f16x8*)(bp + 512);
            acc[nt]  = __builtin_amdgcn_mfma_f32_16x16x32_f16(va[kk], bh, acc[nt], 0, 0, 0);
            acc2[nt] = __builtin_amdgcn_mfma_f32_16x16x32_f16(va[kk], bl, acc2[nt], 0, 0, 0);
            acc2[nt] = __builtin_amdgcn_mfma_f32_16x16x32_f16(vl[kk], bh, acc2[nt], 0, 0, 0);
        }
    }

    const int colg = lane & 15;
    const int rg   = lane >> 4;
#pragma unroll
    for (int nt = 0; nt < 4; ++nt) {
#pragma unroll
        for (int j = 0; j < 4; ++j) {
            const float r = acc[nt][j] + acc2[nt][j] * (1.f / 4096.f);
            const int n  = n0 + w * 16 + rg * 4 + j;
            const int co = nt * 16 + colg;
            if (n < N && co < 54)
                P[(size_t)(co >> 1) * N * 2 + (size_t)n * 2 + (co & 1)] = r;
        }
    }
}

// score(S) = sum_k P[k][nbr(S,k)]  (f32, k-ordered like the reference);
// also fills the coords columns of ppn.
__global__ __launch_bounds__(256)
void reduce_score(const float* __restrict__ P, const int* __restrict__ nbr,
                  const int* __restrict__ coords, float* __restrict__ ppn, int N)
{
    const int site = blockIdx.x * 256 + threadIdx.x;
    if (site >= N) return;
    float s0 = 0.f, s1 = 0.f;
    const size_t pl = (size_t)N * 2;
#pragma unroll
    for (int k = 0; k < 27; ++k) {
        const int idx = nbr[(size_t)site * 27 + k];
        if (idx >= 0) {
            const float2 p = *(const float2*)(P + (size_t)k * pl + (size_t)idx * 2);
            s0 += p.x; s1 += p.y;
        }
    }
    float* row = ppn + (size_t)site * 6;
    const int* cr = coords + (size_t)site * 4;
    row[0] = (float)cr[0]; row[1] = (float)cr[1];
    row[2] = (float)cr[2]; row[3] = (float)cr[3];
    row[4] = s0; row[5] = s1;
}

// ---------------------------------------------------------------------------
// Pre-pass: f32 rows (optionally x att-mask) -> f16 split planes, plus a
// zero row at index N (gather target for missing neighbors / tail sites).
// ---------------------------------------------------------------------------
template<int TERMS>
__global__ __launch_bounds__(256)
void prepass(const float* __restrict__ f, const float* __restrict__ att,
             f16* __restrict__ dst, size_t plane, int C4, int N)
{
    const size_t i = (size_t)blockIdx.x * 256 + threadIdx.x;
    const size_t total = (size_t)(N + 1) * C4;
    if (i >= total) return;
    const int row = (int)(i / C4);
    float4 v = make_float4(0.f, 0.f, 0.f, 0.f);
    if (row < N) {
        v = *(const float4*)(f + i * 4);
        if (att != nullptr) {
            const float a = att[row];
            v.x *= a; v.y *= a; v.z *= a; v.w *= a;
        }
    }
    const float xs[4] = {v.x, v.y, v.z, v.w};
    f16x4 hi, lo;
#pragma unroll
    for (int j = 0; j < 4; ++j) {
        const f16 h = (f16)xs[j];
        hi[j] = h;
        lo[j] = (f16)((xs[j] - (float)h) * 4096.f);
    }
    *(f16x4*)(dst + i * 4) = hi;
    if constexpr (TERMS == 2)
        *(f16x4*)(dst + plane + i * 4) = lo;
}

// Pack fp32 W[27][C][CO_real] into fragment chunks:
// chunk id = ((((k*CS + cs)*KK + kk)*NTB + nt)*TERMS + term), 512 f16 each.
__global__ __launch_bounds__(256)
void pack_w_f16(const float* __restrict__ W, f16* __restrict__ Wb,
                int C, int CO_real, int CS, int NTB, int TERMS)
{
    const int KK = C / 32;
    const int total = 27 * CS * KK * NTB * TERMS * 64;
    const int t = blockIdx.x * blockDim.x + threadIdx.x;
    if (t >= total) return;
    const int lane = t & 63;
    int cid = t >> 6;
    const int term = cid % TERMS; cid /= TERMS;
    const int nt   = cid % NTB;   cid /= NTB;
    const int kk   = cid % KK;    cid /= KK;
    const int cs   = cid % CS;
    const int k    = cid / CS;
    const int co   = (cs * NTB + nt) * 16 + (lane & 15);
#pragma unroll
    for (int j = 0; j < 8; ++j) {
        const int ci = kk * 32 + (lane >> 4) * 8 + j;
        const float x = (co < CO_real) ? W[((size_t)k * C + ci) * CO_real + co] : 0.f;
        const f16 h = (f16)x;
        Wb[(size_t)t * 8 + j] = (term == 0) ? h : (f16)((x - (float)h) * 4096.f);
    }
}

// Pack score weights [27][C][2] as a flat [C x 54->64] fragment set,
// chunk id = ((kk*4 + nt)*2 + term); flat col co = 2k + c.
__global__ __launch_bounds__(256)
void pack_ws_flat(const float* __restrict__ W, f16* __restrict__ Wb, int C)
{
    const int KK = C / 32;
    const int total = KK * 4 * 2 * 64;
    const int t = blockIdx.x * blockDim.x + threadIdx.x;
    if (t >= total) return;
    const int lane = t & 63;
    int cid = t >> 6;
    const int term = cid % 2;
    const int nt   = (cid >> 1) % 4;
    const int kk   = cid >> 3;
    const int co   = nt * 16 + (lane & 15);
#pragma unroll
    for (int j = 0; j < 8; ++j) {
        const int ci = kk * 32 + (lane >> 4) * 8 + j;
        const float x = (co < 54) ? W[((size_t)(co >> 1) * C + ci) * 2 + (co & 1)] : 0.f;
        const f16 h = (f16)x;
        Wb[(size_t)t * 8 + j] = (term == 0) ? h : (f16)((x - (float)h) * 4096.f);
    }
}

// Pack the fused head [27][32][{3|2|5}->10] directly into fragment chunks
// (chunk per k; single term).
__global__ __launch_bounds__(256)
void pack_wh_frag(const float* __restrict__ wp, const float* __restrict__ ws,
                  const float* __restrict__ wt, f16* __restrict__ Wb)
{
    const int t = blockIdx.x * blockDim.x + threadIdx.x;
    if (t >= 27 * 64) return;
    const int lane = t & 63;
    const int k    = t >> 6;
    const int co   = lane & 15;
#pragma unroll
    for (int j = 0; j < 8; ++j) {
        const int ci = (lane >> 4) * 8 + j;
        float x = 0.f;
        if (co < 3)       x = wp[((size_t)k * 32 + ci) * 3 + co];
        else if (co < 5)  x = ws[((size_t)k * 32 + ci) * 2 + (co - 3)];
        else if (co < 10) x = wt[((size_t)k * 32 + ci) * 5 + (co - 5)];
        Wb[(size_t)t * 8 + j] = (f16)x;
    }
}

__global__ __launch_bounds__(256)
void att_kernel(const float* __restrict__ ppn, const int* __restrict__ parent,
                float* __restrict__ att, int N)
{
    const int i = blockIdx.x * blockDim.x + threadIdx.x;
    if (i >= N) return;
    const int p = parent[i];
    const float s0 = ppn[(size_t)p * 6 + 4];
    const float s1 = ppn[(size_t)p * 6 + 5];
    const float m  = fmaxf(s0, s1);
    const float e0 = expf(s0 - m);
    const float e1 = expf(s1 - m);
    const float p1 = e1 / (e0 + e1);
    att[i] = (p1 > 0.8f) ? 1.f : 0.f;
}

extern "C" void kernel_launch(void* const* d_in, const int* in_sizes, int n_in,
                              void* d_out, int out_size, void* d_ws, size_t ws_size,
                              hipStream_t stream)
{
    const float* f1       = (const float*)d_in[0];
    const float* f2       = (const float*)d_in[1];
    const float* f3       = (const float*)d_in[2];
    const float* w1_conv  = (const float*)d_in[3];
    const float* w1_score = (const float*)d_in[4];
    const float* w2_conv  = (const float*)d_in[5];
    const float* w2_score = (const float*)d_in[6];
    const float* w3_conv  = (const float*)d_in[7];
    const float* w3_pix   = (const float*)d_in[8];
    const float* w3_score = (const float*)d_in[9];
    const float* w3_type  = (const float*)d_in[10];
    const int* coords1    = (const int*)d_in[11];
    const int* coords2    = (const int*)d_in[12];
    const int* nbr1       = (const int*)d_in[13];
    const int* nbr2       = (const int*)d_in[14];
    const int* nbr3       = (const int*)d_in[15];
    const int* parent12   = (const int*)d_in[16];
    const int* parent23   = (const int*)d_in[17];

    const int N1 = in_sizes[0] / 160;   // 20000
    const int N2 = in_sizes[1] / 96;    // 160000
    const int N3 = in_sizes[2] / 32;    // 320000

    // Output layout: points[N3,10] | ppn1[N1,6] | ppn2[N2,6] | att[N2] | att2[N3]
    float* points = (float*)d_out;
    float* ppn1   = points + (size_t)N3 * 10;
    float* ppn2   = ppn1 + (size_t)N1 * 6;
    float* attn   = ppn2 + (size_t)N2 * 6;
    float* attn2  = attn + (size_t)N2;

    // Workspace (all conv inputs have N+1 rows; row N = zeros).
    const size_t p1 = (size_t)(N1 + 1) * 160;
    const size_t p2 = (size_t)(N2 + 1) * 96;
    f16* f1s  = (f16*)d_ws;           // 2*p1
    f16* xs   = f1s + 2 * p1;         // 2*p1
    f16* f2s  = xs + 2 * p1;          // 2*p2
    f16* ys   = f2s + 2 * p2;         // 2*p2
    float* P1 = (float*)f1s;          // 27*N1*2 f32
    f16* f3s  = f1s;                  // (N3+1)*32 f16 (reuses f1s+xs)
    float* P2 = (float*)f2s;          // 27*N2*2 f32
    f16* zs   = f2s;                  // (N3+1)*32 f16 (after P2 dead)
    f16* Wb1  = ys + 2 * p2;          // 2700 chunks
    f16* Wb2  = Wb1 + (size_t)2700 * 512;   // 972
    f16* Wb3  = Wb2 + (size_t)972 * 512;    // 54
    f16* Wbh  = Wb3 + (size_t)54 * 512;     // 27
    f16* Wsf1 = Wbh + (size_t)27 * 512;     // 40 (score1 flat)
    f16* Wsf2 = Wsf1 + (size_t)40 * 512;    // 24 (score2 flat)

    // ---- weight packing ----
    // conv1: CS=2, 5 col-tiles per cs
    pack_w_f16<<<(2700 * 64 + 255) / 256, 256, 0, stream>>>(w1_conv, Wb1, 160, 160, 2, 5, 2);
    // conv2: CS=3, 2 col-tiles per cs
    pack_w_f16<<<(972 * 64 + 255) / 256, 256, 0, stream>>>(w2_conv, Wb2, 96, 96, 3, 2, 2);
    pack_w_f16<<<(54 * 64 + 255) / 256, 256, 0, stream>>>(w3_conv, Wb3, 32, 32, 1, 2, 1);
    pack_wh_frag<<<(27 * 64 + 255) / 256, 256, 0, stream>>>(w3_pix, w3_score, w3_type, Wbh);
    pack_ws_flat<<<(40 * 64 + 255) / 256, 256, 0, stream>>>(w1_score, Wsf1, 160);
    pack_ws_flat<<<(24 * 64 + 255) / 256, 256, 0, stream>>>(w2_score, Wsf2, 96);

    // ---- level 1 ----
    prepass<2><<<(int)(((size_t)(N1 + 1) * 40 + 255) / 256), 256, 0, stream>>>(
        f1, nullptr, f1s, p1, 40, N1);
    // conv1: C=160 NTB=5 CS=2 WCO=1 MROW=1, sbuf (50KB LDS, 2 barriers/k).
    // ~110 total regs -> 4 waves/SIMD, 2 blocks/CU co-resident.
    conv_mfma<160, 5, 2, 1, 2, 8, 2, 2, 0, 1><<<160 * 2, 512, 0, stream>>>(
        f1s, p1, nbr1, Wb1, xs, 160, 0, p1, 160, N1, N1 + 1, 160);
    pgemm_score<160><<<(N1 + 63) / 64, 256, 0, stream>>>(xs, p1, Wsf1, P1, N1);
    reduce_score<<<(N1 + 255) / 256, 256, 0, stream>>>(P1, nbr1, coords1, ppn1, N1);
    att_kernel<<<(N2 + 255) / 256, 256, 0, stream>>>(ppn1, parent12, attn, N2);

    // ---- level 2 ----
    prepass<2><<<(int)(((size_t)(N2 + 1) * 24 + 255) / 256), 256, 0, stream>>>(
        f2, attn, f2s, p2, 24, N2);
    // conv2: C=96 NTB=2 CS=3 WCO=1 MROW=2, dbuf (24KB LDS, 1 barrier/k).
    // acc 32 AGPR + arch ~75 = ~107 <= 128 -> 4 waves/SIMD (R10 fix).
    // ROWS=256, tiles=625 -> pad 632, nwg=1896 (%8==0); cs-twins adjacent
    // in gid order -> same XCD -> A re-reads are L2 hits.
    conv_mfma<96, 2, 3, 1, 2, 8, 1, 2, 0, 2><<<632 * 3, 512, 0, stream>>>(
        f2s, p2, nbr2, Wb2, ys, 96, 0, p2, 96, N2, N2 + 1, 632);
    pgemm_score<96><<<(N2 + 63) / 64, 256, 0, stream>>>(ys, p2, Wsf2, P2, N2);
    reduce_score<<<(N2 + 255) / 256, 256, 0, stream>>>(P2, nbr2, coords2, ppn2, N2);
    att_kernel<<<(N3 + 255) / 256, 256, 0, stream>>>(ppn2, parent23, attn2, N3);

    // ---- level 3 (points chain, single-term f16) ----
    prepass<1><<<(int)(((size_t)(N3 + 1) * 8 + 255) / 256), 256, 0, stream>>>(
        f3, attn2, f3s, 0, 8, N3);
    // conv3: C=32 NTB=2 whole-B (54KB), no k-loop barriers, PIPEA.
    conv_mfma<32, 2, 1, 1, 1, 8, 0, 1, 1, 1><<<2504, 512, 0, stream>>>(
        f3s, 0, nbr3, Wb3, zs, 32, 0, 0, 32, N3, N3 + 1, 2504);
    // head: C=32 NTB=1 whole-B (27KB), PIPEA.
    conv_mfma<32, 1, 1, 1, 1, 8, 0, 0, 1, 1><<<2504, 512, 0, stream>>>(
        zs, 0, nbr3, Wbh, points, 10, 0, 0, 10, N3, N3, 2504);
}

// Round 12
// 622.888 us; speedup vs baseline: 1.2533x; 1.2533x over previous
//
#include <hip/hip_runtime.h>
#include <cstddef>

typedef _Float16 f16;
typedef f16 f16x4 __attribute__((ext_vector_type(4)));
typedef f16 f16x8 __attribute__((ext_vector_type(8)));
typedef float f32x4 __attribute__((ext_vector_type(4)));

// async global->LDS, 16B per lane. LDS dest = uniform base + lane*16 (HW);
// global src is per-lane.
__device__ inline void gld_lds16(const f16* g, f16* l) {
    __builtin_amdgcn_global_load_lds(
        (const __attribute__((address_space(1))) void*)g,
        (__attribute__((address_space(3))) void*)l, 16, 0, 0);
}

// ---------------------------------------------------------------------------
// MFMA submanifold conv, A-direct / B-in-LDS.
//  - GEOMETRY RULE (R10/R11 lesson): MROW=2 variants (310/409us) always lose
//    to plain MROW=1 (R5: 234us) regardless of LDS/VGPR budget — occupancy
//    collapses to ~22% for reasons the register arithmetic doesn't predict.
//    Stick to MROW=1, NTB=3, CS=2 for conv2 (best measured).
//  - WAVES=4 for conv2 (R12 single-variable change): same 36KB dbuf but
//    4 co-resident blocks/CU = 4 independent barrier groups covering each
//    other's per-k stage drains (vs 2 at WAVES=8).
//  - A fragments: per-lane 16B loads from pre-split f16 planes (hi at base,
//    lo at +in_plane). Row N = zeros (missing neighbors / tails).
//  - TERMS=2: Markidis f16 split (hi + lo*2^12), 3 MFMAs/pair -> ~fp32
//    accuracy (mask-threshold chain). TERMS=1: plain f16 (points chain).
//  - BMODE 0: whole weight set in LDS, no k barriers (PIPEA reg-dbuf A).
//    BMODE 1: per-k LDS double-buffer, 1 barrier/k (A(k+1) issued pre-drain).
//    BMODE 2: per-k single buffer, 2 barriers/k (50KB k-slices).
//  - Bijective XCD-chunk swizzle (nwg % 8 == 0).
// ---------------------------------------------------------------------------
template<int C, int NTB, int CS, int WCO, int TERMS, int WAVES, int BMODE,
         int OUTM, int PIPEA, int MROW>
__global__ __launch_bounds__(WAVES * 64)
void conv_mfma(const f16* __restrict__ fin, size_t in_plane,
               const int* __restrict__ nbr,
               const f16* __restrict__ Wb,
               void* __restrict__ outv, int ostride, int ooff, size_t out_plane,
               int CO_real, int N, int Nstore, int tilesPad)
{
    constexpr int KK   = C / 32;
    constexpr int KKL  = (TERMS == 2) ? KK : 1;
    constexpr int NTBT = WCO * NTB;             // col tiles per (k, cs)
    constexpr int CH   = KK * NTBT * TERMS;     // 1KB fragment chunks per (k,cs)
    constexpr int WROW = WAVES / WCO;
    constexpr int ROWS = WROW * MROW * 16;
    constexpr int BUFS = (BMODE == 0) ? 27 : ((BMODE == 1) ? 2 : 1);
    static_assert(!(BMODE == 0 && MROW != 1), "BMODE0 path is MROW=1");
    __shared__ f16 sB[BUFS * CH * 512];

    const int lane = threadIdx.x & 63;
    const int w    = threadIdx.x >> 6;
    const int wco  = w % WCO;
    const int wrow = w / WCO;
    int gid = blockIdx.x;
    { const int q = (tilesPad * CS) >> 3; gid = (gid & 7) * q + (gid >> 3); }
    const int tile = gid / CS;
    const int cs   = gid - tile * CS;
    const int n0   = tile * ROWS;
    const int NZ   = N;                          // zero row
    const int h8   = (lane >> 4) * 8;

    int  site[MROW];
    bool sv[MROW];
#pragma unroll
    for (int r = 0; r < MROW; ++r) {
        site[r] = n0 + (wrow * MROW + r) * 16 + (lane & 15);
        sv[r]   = site[r] < N;
    }

    auto nbrIdx = [&](int r, int k) -> int {
        int v = sv[r] ? nbr[(size_t)site[r] * 27 + k] : -1;
        return (v < 0) ? NZ : v;
    };

    auto stageK = [&](int k, int buf) {
        const f16* src = Wb + ((size_t)(k * CS + cs) * CH) * 512 + lane * 8;
        f16* dst = &sB[(size_t)buf * CH * 512];
#pragma unroll
        for (int c = w; c < CH; c += WAVES)
            gld_lds16(src + (size_t)c * 512, dst + (size_t)c * 512);
    };

    f32x4 acc[MROW * NTB], acc2[MROW * NTB];
#pragma unroll
    for (int i = 0; i < MROW * NTB; ++i) {
        acc[i]  = (f32x4){0.f, 0.f, 0.f, 0.f};
        acc2[i] = (f32x4){0.f, 0.f, 0.f, 0.f};
    }

    f16x8 va[MROW * KK], vl[MROW * KKL];
    f16x8 vaB[(BMODE == 0 && PIPEA) ? KK : 1], vlB[(BMODE == 0 && PIPEA) ? KKL : 1];

    auto loadA = [&](int idx, f16x8* pva, f16x8* pvl) {
        const f16* arow = fin + (size_t)idx * C + h8;
#pragma unroll
        for (int kk = 0; kk < KK; ++kk) {
            pva[kk] = *(const f16x8*)(arow + kk * 32);
            if constexpr (TERMS == 2)
                pvl[kk] = *(const f16x8*)(arow + in_plane + kk * 32);
        }
    };

    auto mfmaPhase = [&](const f16x8* pva, const f16x8* pvl, int kbuf) {
        const f16* sBc = &sB[(size_t)kbuf * CH * 512] + lane * 8;
#pragma unroll
        for (int kk = 0; kk < KK; ++kk) {
#pragma unroll
            for (int nt = 0; nt < NTB; ++nt) {
                const f16* bp = sBc + (size_t)((kk * NTBT + wco * NTB + nt) * TERMS) * 512;
                const f16x8 bh = *(const f16x8*)bp;
                if constexpr (TERMS == 2) {
                    const f16x8 bl = *(const f16x8*)(bp + 512);
#pragma unroll
                    for (int r = 0; r < MROW; ++r) {
                        acc[r * NTB + nt]  = __builtin_amdgcn_mfma_f32_16x16x32_f16(
                            pva[r * KK + kk], bh, acc[r * NTB + nt], 0, 0, 0);
                        acc2[r * NTB + nt] = __builtin_amdgcn_mfma_f32_16x16x32_f16(
                            pva[r * KK + kk], bl, acc2[r * NTB + nt], 0, 0, 0);
                        acc2[r * NTB + nt] = __builtin_amdgcn_mfma_f32_16x16x32_f16(
                            pvl[r * KK + kk], bh, acc2[r * NTB + nt], 0, 0, 0);
                    }
                } else {
#pragma unroll
                    for (int r = 0; r < MROW; ++r)
                        acc[r * NTB + nt] = __builtin_amdgcn_mfma_f32_16x16x32_f16(
                            pva[r * KK + kk], bh, acc[r * NTB + nt], 0, 0, 0);
                }
            }
        }
    };

    if constexpr (BMODE == 1) {
        // ---- per-k dbuf; 1 barrier/k; A(k+1) issued pre-drain ----
        int idxN[MROW];
#pragma unroll
        for (int r = 0; r < MROW; ++r)
            loadA(nbrIdx(r, 0), &va[r * KK], &vl[r * KKL]);
        stageK(0, 0);
#pragma unroll
        for (int r = 0; r < MROW; ++r) idxN[r] = nbrIdx(r, 1);
        __syncthreads();                       // drains A(0) + B(0)

        for (int k = 0; k < 27; ++k) {
            if (k + 1 < 27) stageK(k + 1, (k + 1) & 1);
            mfmaPhase(va, vl, k & 1);          // A(k), B(k) complete
            if (k + 1 < 27) {
#pragma unroll
                for (int r = 0; r < MROW; ++r)
                    loadA(idxN[r], &va[r * KK], &vl[r * KKL]);
#pragma unroll
                for (int r = 0; r < MROW; ++r)
                    idxN[r] = (k + 2 < 27) ? nbrIdx(r, k + 2) : NZ;
                __syncthreads();               // drains A(k+1) + B(k+1)
            }
        }
    } else if constexpr (BMODE == 2) {
        // ---- per-k single buffer; 2 barriers/k (covered by co-res block) ----
        int idxN[MROW];
#pragma unroll
        for (int r = 0; r < MROW; ++r)
            loadA(nbrIdx(r, 0), &va[r * KK], &vl[r * KKL]);
#pragma unroll
        for (int r = 0; r < MROW; ++r) idxN[r] = nbrIdx(r, 1);

        for (int k = 0; k < 27; ++k) {
            stageK(k, 0);                      // prev reads done (barrier below)
            __syncthreads();                   // drains stage(k) + A(k)
            mfmaPhase(va, vl, 0);
            if (k + 1 < 27) {
#pragma unroll
                for (int r = 0; r < MROW; ++r)
                    loadA(idxN[r], &va[r * KK], &vl[r * KKL]);
#pragma unroll
                for (int r = 0; r < MROW; ++r)
                    idxN[r] = (k + 2 < 27) ? nbrIdx(r, k + 2) : NZ;
                __syncthreads();               // B(k) reads done before restage
            }
        }
    } else {
        // ---- whole-B resident, no k-loop barriers; PIPEA A reg-dbuf ----
#pragma unroll
        for (int c = w; c < 27 * CH; c += WAVES)
            gld_lds16(Wb + (size_t)c * 512 + lane * 8, &sB[(size_t)c * 512]);
        int idxC = nbrIdx(0, 0);
        loadA(idxC, va, vl);
        int idxN = nbrIdx(0, 1);
        __syncthreads();

        if constexpr (PIPEA) {
            auto body = [&](int k, f16x8* vac, f16x8* vlc, f16x8* van, f16x8* vln) {
                if (k >= 27) return;
                if (k + 1 < 27) {
                    loadA(idxN, van, vln);
                    idxN = (k + 2 < 27) ? nbrIdx(0, k + 2) : NZ;
                }
                mfmaPhase(vac, vlc, k);
            };
            for (int k2 = 0; k2 < 27; k2 += 2) {
                body(k2, va, vl, vaB, vlB);
                body(k2 + 1, vaB, vlB, va, vl);
            }
        } else {
            for (int k = 0; k < 27; ++k) {
                mfmaPhase(va, vl, k);
                if (k + 1 < 27) {
                    loadA(idxN, va, vl);
                    idxN = (k + 2 < 27) ? nbrIdx(0, k + 2) : NZ;
                }
            }
        }
    }

    // ---- epilogue: D col=lane&15, row=(lane>>4)*4+j ----
    const int colg = lane & 15;
    const int rg   = lane >> 4;
#pragma unroll
    for (int r = 0; r < MROW; ++r) {
#pragma unroll
        for (int nt = 0; nt < NTB; ++nt) {
#pragma unroll
            for (int j = 0; j < 4; ++j) {
                float v = acc[r * NTB + nt][j];
                if constexpr (TERMS == 2) v += acc2[r * NTB + nt][j] * (1.f / 4096.f);
                const int n  = n0 + (wrow * MROW + r) * 16 + rg * 4 + j;
                const int co = ((cs * WCO + wco) * NTB + nt) * 16 + colg;
                if (n < Nstore && co < CO_real) {
                    if constexpr (OUTM == 0) {
                        ((float*)outv)[(size_t)n * ostride + ooff + co] = v;
                    } else if constexpr (OUTM == 1) {
                        ((f16*)outv)[(size_t)n * ostride + co] = (f16)v;
                    } else {
                        f16* o = (f16*)outv;
                        const f16 h = (f16)v;
                        o[(size_t)n * ostride + co] = h;
                        o[out_plane + (size_t)n * ostride + co] = (f16)((v - (float)h) * 4096.f);
                    }
                }
            }
        }
    }
}

// ---------------------------------------------------------------------------
// P-factorized score: P[k][R][c] = f[R] @ Ws[k][:,c] as ONE dense GEMM
// f[N x C] @ Wflat[C x 54->64] (no gather). P is f32 [27][N][2].
// ---------------------------------------------------------------------------
template<int C>
__global__ __launch_bounds__(256)
void pgemm_score(const f16* __restrict__ fin, size_t plane,
                 const f16* __restrict__ Wb,   // (C/32)*4*2 chunks
                 float* __restrict__ P, int N)
{
    constexpr int KK = C / 32;
    constexpr int CH = KK * 4 * 2;
    __shared__ f16 sB[CH * 512];

    const int tid  = threadIdx.x;
    const int lane = tid & 63;
    const int w    = tid >> 6;

    const int n0 = blockIdx.x * 64;
    int site = n0 + w * 16 + (lane & 15);
    if (site > N) site = N;                 // zero row for tails
    const int h8 = (lane >> 4) * 8;

    f16x8 va[KK], vl[KK];
    const f16* arow = fin + (size_t)site * C + h8;
#pragma unroll
    for (int kk = 0; kk < KK; ++kk) {
        va[kk] = *(const f16x8*)(arow + kk * 32);
        vl[kk] = *(const f16x8*)(arow + plane + kk * 32);
    }
    for (int c = w; c < CH; c += 4)
        gld_lds16(Wb + (size_t)c * 512 + lane * 8, &sB[(size_t)c * 512]);

    f32x4 acc[4], acc2[4];
#pragma unroll
    for (int nt = 0; nt < 4; ++nt) {
        acc[nt]  = (f32x4){0.f, 0.f, 0.f, 0.f};
        acc2[nt] = (f32x4){0.f, 0.f, 0.f, 0.f};
    }
    __syncthreads();

#pragma unroll
    for (int kk = 0; kk < KK; ++kk) {
#pragma unroll
        for (int nt = 0; nt < 4; ++nt) {
            const f16* bp = &sB[(size_t)((kk * 4 + nt) * 2) * 512] + lane * 8;
            const f16x8 bh = *(const f16x8*)bp;
            const f16x8 bl = *(const f16x8*)(bp + 512);
            acc[nt]  = __builtin_amdgcn_mfma_f32_16x16x32_f16(va[kk], bh, acc[nt], 0, 0, 0);
            acc2[nt] = __builtin_amdgcn_mfma_f32_16x16x32_f16(va[kk], bl, acc2[nt], 0, 0, 0);
            acc2[nt] = __builtin_amdgcn_mfma_f32_16x16x32_f16(vl[kk], bh, acc2[nt], 0, 0, 0);
        }
    }

    const int colg = lane & 15;
    const int rg   = lane >> 4;
#pragma unroll
    for (int nt = 0; nt < 4; ++nt) {
#pragma unroll
        for (int j = 0; j < 4; ++j) {
            const float r = acc[nt][j] + acc2[nt][j] * (1.f / 4096.f);
            const int n  = n0 + w * 16 + rg * 4 + j;
            const int co = nt * 16 + colg;
            if (n < N && co < 54)
                P[(size_t)(co >> 1) * N * 2 + (size_t)n * 2 + (co & 1)] = r;
        }
    }
}

// score(S) = sum_k P[k][nbr(S,k)]  (f32, k-ordered like the reference);
// also fills the coords columns of ppn.
__global__ __launch_bounds__(256)
void reduce_score(const float* __restrict__ P, const int* __restrict__ nbr,
                  const int* __restrict__ coords, float* __restrict__ ppn, int N)
{
    const int site = blockIdx.x * 256 + threadIdx.x;
    if (site >= N) return;
    float s0 = 0.f, s1 = 0.f;
    const size_t pl = (size_t)N * 2;
#pragma unroll
    for (int k = 0; k < 27; ++k) {
        const int idx = nbr[(size_t)site * 27 + k];
        if (idx >= 0) {
            const float2 p = *(const float2*)(P + (size_t)k * pl + (size_t)idx * 2);
            s0 += p.x; s1 += p.y;
        }
    }
    float* row = ppn + (size_t)site * 6;
    const int* cr = coords + (size_t)site * 4;
    row[0] = (float)cr[0]; row[1] = (float)cr[1];
    row[2] = (float)cr[2]; row[3] = (float)cr[3];
    row[4] = s0; row[5] = s1;
}

// ---------------------------------------------------------------------------
// Pre-pass: f32 rows (optionally x att-mask) -> f16 split planes, plus a
// zero row at index N (gather target for missing neighbors / tail sites).
// ---------------------------------------------------------------------------
template<int TERMS>
__global__ __launch_bounds__(256)
void prepass(const float* __restrict__ f, const float* __restrict__ att,
             f16* __restrict__ dst, size_t plane, int C4, int N)
{
    const size_t i = (size_t)blockIdx.x * 256 + threadIdx.x;
    const size_t total = (size_t)(N + 1) * C4;
    if (i >= total) return;
    const int row = (int)(i / C4);
    float4 v = make_float4(0.f, 0.f, 0.f, 0.f);
    if (row < N) {
        v = *(const float4*)(f + i * 4);
        if (att != nullptr) {
            const float a = att[row];
            v.x *= a; v.y *= a; v.z *= a; v.w *= a;
        }
    }
    const float xs[4] = {v.x, v.y, v.z, v.w};
    f16x4 hi, lo;
#pragma unroll
    for (int j = 0; j < 4; ++j) {
        const f16 h = (f16)xs[j];
        hi[j] = h;
        lo[j] = (f16)((xs[j] - (float)h) * 4096.f);
    }
    *(f16x4*)(dst + i * 4) = hi;
    if constexpr (TERMS == 2)
        *(f16x4*)(dst + plane + i * 4) = lo;
}

// Pack fp32 W[27][C][CO_real] into fragment chunks:
// chunk id = ((((k*CS + cs)*KK + kk)*NTB + nt)*TERMS + term), 512 f16 each.
__global__ __launch_bounds__(256)
void pack_w_f16(const float* __restrict__ W, f16* __restrict__ Wb,
                int C, int CO_real, int CS, int NTB, int TERMS)
{
    const int KK = C / 32;
    const int total = 27 * CS * KK * NTB * TERMS * 64;
    const int t = blockIdx.x * blockDim.x + threadIdx.x;
    if (t >= total) return;
    const int lane = t & 63;
    int cid = t >> 6;
    const int term = cid % TERMS; cid /= TERMS;
    const int nt   = cid % NTB;   cid /= NTB;
    const int kk   = cid % KK;    cid /= KK;
    const int cs   = cid % CS;
    const int k    = cid / CS;
    const int co   = (cs * NTB + nt) * 16 + (lane & 15);
#pragma unroll
    for (int j = 0; j < 8; ++j) {
        const int ci = kk * 32 + (lane >> 4) * 8 + j;
        const float x = (co < CO_real) ? W[((size_t)k * C + ci) * CO_real + co] : 0.f;
        const f16 h = (f16)x;
        Wb[(size_t)t * 8 + j] = (term == 0) ? h : (f16)((x - (float)h) * 4096.f);
    }
}

// Pack score weights [27][C][2] as a flat [C x 54->64] fragment set,
// chunk id = ((kk*4 + nt)*2 + term); flat col co = 2k + c.
__global__ __launch_bounds__(256)
void pack_ws_flat(const float* __restrict__ W, f16* __restrict__ Wb, int C)
{
    const int KK = C / 32;
    const int total = KK * 4 * 2 * 64;
    const int t = blockIdx.x * blockDim.x + threadIdx.x;
    if (t >= total) return;
    const int lane = t & 63;
    int cid = t >> 6;
    const int term = cid % 2;
    const int nt   = (cid >> 1) % 4;
    const int kk   = cid >> 3;
    const int co   = nt * 16 + (lane & 15);
#pragma unroll
    for (int j = 0; j < 8; ++j) {
        const int ci = kk * 32 + (lane >> 4) * 8 + j;
        const float x = (co < 54) ? W[((size_t)(co >> 1) * C + ci) * 2 + (co & 1)] : 0.f;
        const f16 h = (f16)x;
        Wb[(size_t)t * 8 + j] = (term == 0) ? h : (f16)((x - (float)h) * 4096.f);
    }
}

// Pack the fused head [27][32][{3|2|5}->10] directly into fragment chunks
// (chunk per k; single term).
__global__ __launch_bounds__(256)
void pack_wh_frag(const float* __restrict__ wp, const float* __restrict__ ws,
                  const float* __restrict__ wt, f16* __restrict__ Wb)
{
    const int t = blockIdx.x * blockDim.x + threadIdx.x;
    if (t >= 27 * 64) return;
    const int lane = t & 63;
    const int k    = t >> 6;
    const int co   = lane & 15;
#pragma unroll
    for (int j = 0; j < 8; ++j) {
        const int ci = (lane >> 4) * 8 + j;
        float x = 0.f;
        if (co < 3)       x = wp[((size_t)k * 32 + ci) * 3 + co];
        else if (co < 5)  x = ws[((size_t)k * 32 + ci) * 2 + (co - 3)];
        else if (co < 10) x = wt[((size_t)k * 32 + ci) * 5 + (co - 5)];
        Wb[(size_t)t * 8 + j] = (f16)x;
    }
}

__global__ __launch_bounds__(256)
void att_kernel(const float* __restrict__ ppn, const int* __restrict__ parent,
                float* __restrict__ att, int N)
{
    const int i = blockIdx.x * blockDim.x + threadIdx.x;
    if (i >= N) return;
    const int p = parent[i];
    const float s0 = ppn[(size_t)p * 6 + 4];
    const float s1 = ppn[(size_t)p * 6 + 5];
    const float m  = fmaxf(s0, s1);
    const float e0 = expf(s0 - m);
    const float e1 = expf(s1 - m);
    const float p1 = e1 / (e0 + e1);
    att[i] = (p1 > 0.8f) ? 1.f : 0.f;
}

extern "C" void kernel_launch(void* const* d_in, const int* in_sizes, int n_in,
                              void* d_out, int out_size, void* d_ws, size_t ws_size,
                              hipStream_t stream)
{
    const float* f1       = (const float*)d_in[0];
    const float* f2       = (const float*)d_in[1];
    const float* f3       = (const float*)d_in[2];
    const float* w1_conv  = (const float*)d_in[3];
    const float* w1_score = (const float*)d_in[4];
    const float* w2_conv  = (const float*)d_in[5];
    const float* w2_score = (const float*)d_in[6];
    const float* w3_conv  = (const float*)d_in[7];
    const float* w3_pix   = (const float*)d_in[8];
    const float* w3_score = (const float*)d_in[9];
    const float* w3_type  = (const float*)d_in[10];
    const int* coords1    = (const int*)d_in[11];
    const int* coords2    = (const int*)d_in[12];
    const int* nbr1       = (const int*)d_in[13];
    const int* nbr2       = (const int*)d_in[14];
    const int* nbr3       = (const int*)d_in[15];
    const int* parent12   = (const int*)d_in[16];
    const int* parent23   = (const int*)d_in[17];

    const int N1 = in_sizes[0] / 160;   // 20000
    const int N2 = in_sizes[1] / 96;    // 160000
    const int N3 = in_sizes[2] / 32;    // 320000

    // Output layout: points[N3,10] | ppn1[N1,6] | ppn2[N2,6] | att[N2] | att2[N3]
    float* points = (float*)d_out;
    float* ppn1   = points + (size_t)N3 * 10;
    float* ppn2   = ppn1 + (size_t)N1 * 6;
    float* attn   = ppn2 + (size_t)N2 * 6;
    float* attn2  = attn + (size_t)N2;

    // Workspace (all conv inputs have N+1 rows; row N = zeros).
    const size_t p1 = (size_t)(N1 + 1) * 160;
    const size_t p2 = (size_t)(N2 + 1) * 96;
    f16* f1s  = (f16*)d_ws;           // 2*p1
    f16* xs   = f1s + 2 * p1;         // 2*p1
    f16* f2s  = xs + 2 * p1;          // 2*p2
    f16* ys   = f2s + 2 * p2;         // 2*p2
    float* P1 = (float*)f1s;          // 27*N1*2 f32
    f16* f3s  = f1s;                  // (N3+1)*32 f16 (reuses f1s+xs)
    float* P2 = (float*)f2s;          // 27*N2*2 f32
    f16* zs   = f2s;                  // (N3+1)*32 f16 (after P2 dead)
    f16* Wb1  = ys + 2 * p2;          // 2700 chunks
    f16* Wb2  = Wb1 + (size_t)2700 * 512;   // 972
    f16* Wb3  = Wb2 + (size_t)972 * 512;    // 54
    f16* Wbh  = Wb3 + (size_t)54 * 512;     // 27
    f16* Wsf1 = Wbh + (size_t)27 * 512;     // 40 (score1 flat)
    f16* Wsf2 = Wsf1 + (size_t)40 * 512;    // 24 (score2 flat)

    // ---- weight packing ----
    // conv1: CS=2, 5 col-tiles per cs
    pack_w_f16<<<(2700 * 64 + 255) / 256, 256, 0, stream>>>(w1_conv, Wb1, 160, 160, 2, 5, 2);
    // conv2: CS=2, 3 col-tiles per cs (R5/R7 best geometry)
    pack_w_f16<<<(972 * 64 + 255) / 256, 256, 0, stream>>>(w2_conv, Wb2, 96, 96, 2, 3, 2);
    pack_w_f16<<<(54 * 64 + 255) / 256, 256, 0, stream>>>(w3_conv, Wb3, 32, 32, 1, 2, 1);
    pack_wh_frag<<<(27 * 64 + 255) / 256, 256, 0, stream>>>(w3_pix, w3_score, w3_type, Wbh);
    pack_ws_flat<<<(40 * 64 + 255) / 256, 256, 0, stream>>>(w1_score, Wsf1, 160);
    pack_ws_flat<<<(24 * 64 + 255) / 256, 256, 0, stream>>>(w2_score, Wsf2, 96);

    // ---- level 1 ----
    prepass<2><<<(int)(((size_t)(N1 + 1) * 40 + 255) / 256), 256, 0, stream>>>(
        f1, nullptr, f1s, p1, 40, N1);
    // conv1: C=160 NTB=5 CS=2 WCO=1 MROW=1, sbuf (50KB LDS, 2 barriers/k).
    // R9's config (contributed to the best 666us total).
    conv_mfma<160, 5, 2, 1, 2, 8, 2, 2, 0, 1><<<160 * 2, 512, 0, stream>>>(
        f1s, p1, nbr1, Wb1, xs, 160, 0, p1, 160, N1, N1 + 1, 160);
    pgemm_score<160><<<(N1 + 63) / 64, 256, 0, stream>>>(xs, p1, Wsf1, P1, N1);
    reduce_score<<<(N1 + 255) / 256, 256, 0, stream>>>(P1, nbr1, coords1, ppn1, N1);
    att_kernel<<<(N2 + 255) / 256, 256, 0, stream>>>(ppn1, parent12, attn, N2);

    // ---- level 2 ----
    prepass<2><<<(int)(((size_t)(N2 + 1) * 24 + 255) / 256), 256, 0, stream>>>(
        f2, attn, f2s, p2, 24, N2);
    // conv2: R5/R7 geometry (NTB=3 CS=2 MROW=1, 36KB dbuf) with WAVES=4:
    // 4 co-resident 256-thr blocks/CU (LDS 4x36=144<=160, VGPR ~56) = 4
    // independent barrier groups covering per-k stage drains (R12's single
    // variable). ROWS=64, tiles=2500 -> pad 2504, nwg=5008 (%8==0).
    conv_mfma<96, 3, 2, 1, 2, 4, 1, 2, 0, 1><<<2504 * 2, 256, 0, stream>>>(
        f2s, p2, nbr2, Wb2, ys, 96, 0, p2, 96, N2, N2 + 1, 2504);
    pgemm_score<96><<<(N2 + 63) / 64, 256, 0, stream>>>(ys, p2, Wsf2, P2, N2);
    reduce_score<<<(N2 + 255) / 256, 256, 0, stream>>>(P2, nbr2, coords2, ppn2, N2);
    att_kernel<<<(N3 + 255) / 256, 256, 0, stream>>>(ppn2, parent23, attn2, N3);

    // ---- level 3 (points chain, single-term f16) ----
    prepass<1><<<(int)(((size_t)(N3 + 1) * 8 + 255) / 256), 256, 0, stream>>>(
        f3, attn2, f3s, 0, 8, N3);
    // conv3: C=32 NTB=2 whole-B (54KB), no k-loop barriers, PIPEA.
    conv_mfma<32, 2, 1, 1, 1, 8, 0, 1, 1, 1><<<2504, 512, 0, stream>>>(
        f3s, 0, nbr3, Wb3, zs, 32, 0, 0, 32, N3, N3 + 1, 2504);
    // head: C=32 NTB=1 whole-B (27KB), PIPEA.
    conv_mfma<32, 1, 1, 1, 1, 8, 0, 0, 1, 1><<<2504, 512, 0, stream>>>(
        zs, 0, nbr3, Wbh, points, 10, 0, 0, 10, N3, N3, 2504);
}

// Round 13
// 607.129 us; speedup vs baseline: 1.2858x; 1.0260x over previous
//
#include <hip/hip_runtime.h>
#include <cstddef>

typedef _Float16 f16;
typedef f16 f16x4 __attribute__((ext_vector_type(4)));
typedef f16 f16x8 __attribute__((ext_vector_type(8)));
typedef float f32x4 __attribute__((ext_vector_type(4)));

// async global->LDS, 16B per lane. LDS dest = uniform base + lane*16 (HW);
// global src is per-lane.
__device__ inline void gld_lds16(const f16* g, f16* l) {
    __builtin_amdgcn_global_load_lds(
        (const __attribute__((address_space(1))) void*)g,
        (__attribute__((address_space(3))) void*)l, 16, 0, 0);
}

// ---------------------------------------------------------------------------
// MFMA submanifold conv, A-direct / B-in-LDS.
//  - GEOMETRY (R5/R7/R12 measured): conv2 best = NTB=3 CS=2 MROW=1 WAVES=8,
//    36KB dbuf (234us). MROW=2 variants and WAVES=4 both lose (occupancy
//    collapse / fewer co-resident barrier groups).
//  - MASK REMAP (R12 lesson): A-gather costs ~60us/GB (R10->R11 CS delta).
//    att zeroes ~84% of f2/f3 rows exactly; nbr remapped so masked gathers
//    hit the single zero row (L1 broadcast) instead of fetching zeros
//    through L2/L3.
//  - A fragments: per-lane 16B loads from pre-split f16 planes (hi at base,
//    lo at +in_plane). Row N = zeros (missing neighbors / tails / masked).
//  - TERMS=2: Markidis f16 split (hi + lo*2^12), 3 MFMAs/pair -> ~fp32
//    accuracy (mask-threshold chain). TERMS=1: plain f16 (points chain).
//  - BMODE 0: whole weight set in LDS, no k barriers (PIPEA reg-dbuf A).
//    BMODE 1: per-k LDS double-buffer, 1 barrier/k (A(k+1) issued pre-drain).
//    BMODE 2: per-k single buffer, 2 barriers/k (50KB k-slices).
//  - Bijective XCD-chunk swizzle (nwg % 8 == 0).
// ---------------------------------------------------------------------------
template<int C, int NTB, int CS, int WCO, int TERMS, int WAVES, int BMODE,
         int OUTM, int PIPEA, int MROW>
__global__ __launch_bounds__(WAVES * 64)
void conv_mfma(const f16* __restrict__ fin, size_t in_plane,
               const int* __restrict__ nbr,
               const f16* __restrict__ Wb,
               void* __restrict__ outv, int ostride, int ooff, size_t out_plane,
               int CO_real, int N, int Nstore, int tilesPad)
{
    constexpr int KK   = C / 32;
    constexpr int KKL  = (TERMS == 2) ? KK : 1;
    constexpr int NTBT = WCO * NTB;             // col tiles per (k, cs)
    constexpr int CH   = KK * NTBT * TERMS;     // 1KB fragment chunks per (k,cs)
    constexpr int WROW = WAVES / WCO;
    constexpr int ROWS = WROW * MROW * 16;
    constexpr int BUFS = (BMODE == 0) ? 27 : ((BMODE == 1) ? 2 : 1);
    static_assert(!(BMODE == 0 && MROW != 1), "BMODE0 path is MROW=1");
    __shared__ f16 sB[BUFS * CH * 512];

    const int lane = threadIdx.x & 63;
    const int w    = threadIdx.x >> 6;
    const int wco  = w % WCO;
    const int wrow = w / WCO;
    int gid = blockIdx.x;
    { const int q = (tilesPad * CS) >> 3; gid = (gid & 7) * q + (gid >> 3); }
    const int tile = gid / CS;
    const int cs   = gid - tile * CS;
    const int n0   = tile * ROWS;
    const int NZ   = N;                          // zero row
    const int h8   = (lane >> 4) * 8;

    int  site[MROW];
    bool sv[MROW];
#pragma unroll
    for (int r = 0; r < MROW; ++r) {
        site[r] = n0 + (wrow * MROW + r) * 16 + (lane & 15);
        sv[r]   = site[r] < N;
    }

    auto nbrIdx = [&](int r, int k) -> int {
        int v = sv[r] ? nbr[(size_t)site[r] * 27 + k] : -1;
        return (v < 0) ? NZ : v;
    };

    auto stageK = [&](int k, int buf) {
        const f16* src = Wb + ((size_t)(k * CS + cs) * CH) * 512 + lane * 8;
        f16* dst = &sB[(size_t)buf * CH * 512];
#pragma unroll
        for (int c = w; c < CH; c += WAVES)
            gld_lds16(src + (size_t)c * 512, dst + (size_t)c * 512);
    };

    f32x4 acc[MROW * NTB], acc2[MROW * NTB];
#pragma unroll
    for (int i = 0; i < MROW * NTB; ++i) {
        acc[i]  = (f32x4){0.f, 0.f, 0.f, 0.f};
        acc2[i] = (f32x4){0.f, 0.f, 0.f, 0.f};
    }

    f16x8 va[MROW * KK], vl[MROW * KKL];
    f16x8 vaB[(BMODE == 0 && PIPEA) ? KK : 1], vlB[(BMODE == 0 && PIPEA) ? KKL : 1];

    auto loadA = [&](int idx, f16x8* pva, f16x8* pvl) {
        const f16* arow = fin + (size_t)idx * C + h8;
#pragma unroll
        for (int kk = 0; kk < KK; ++kk) {
            pva[kk] = *(const f16x8*)(arow + kk * 32);
            if constexpr (TERMS == 2)
                pvl[kk] = *(const f16x8*)(arow + in_plane + kk * 32);
        }
    };

    auto mfmaPhase = [&](const f16x8* pva, const f16x8* pvl, int kbuf) {
        const f16* sBc = &sB[(size_t)kbuf * CH * 512] + lane * 8;
#pragma unroll
        for (int kk = 0; kk < KK; ++kk) {
#pragma unroll
            for (int nt = 0; nt < NTB; ++nt) {
                const f16* bp = sBc + (size_t)((kk * NTBT + wco * NTB + nt) * TERMS) * 512;
                const f16x8 bh = *(const f16x8*)bp;
                if constexpr (TERMS == 2) {
                    const f16x8 bl = *(const f16x8*)(bp + 512);
#pragma unroll
                    for (int r = 0; r < MROW; ++r) {
                        acc[r * NTB + nt]  = __builtin_amdgcn_mfma_f32_16x16x32_f16(
                            pva[r * KK + kk], bh, acc[r * NTB + nt], 0, 0, 0);
                        acc2[r * NTB + nt] = __builtin_amdgcn_mfma_f32_16x16x32_f16(
                            pva[r * KK + kk], bl, acc2[r * NTB + nt], 0, 0, 0);
                        acc2[r * NTB + nt] = __builtin_amdgcn_mfma_f32_16x16x32_f16(
                            pvl[r * KK + kk], bh, acc2[r * NTB + nt], 0, 0, 0);
                    }
                } else {
#pragma unroll
                    for (int r = 0; r < MROW; ++r)
                        acc[r * NTB + nt] = __builtin_amdgcn_mfma_f32_16x16x32_f16(
                            pva[r * KK + kk], bh, acc[r * NTB + nt], 0, 0, 0);
                }
            }
        }
    };

    if constexpr (BMODE == 1) {
        // ---- per-k dbuf; 1 barrier/k; A(k+1) issued pre-drain ----
        int idxN[MROW];
#pragma unroll
        for (int r = 0; r < MROW; ++r)
            loadA(nbrIdx(r, 0), &va[r * KK], &vl[r * KKL]);
        stageK(0, 0);
#pragma unroll
        for (int r = 0; r < MROW; ++r) idxN[r] = nbrIdx(r, 1);
        __syncthreads();                       // drains A(0) + B(0)

        for (int k = 0; k < 27; ++k) {
            if (k + 1 < 27) stageK(k + 1, (k + 1) & 1);
            mfmaPhase(va, vl, k & 1);          // A(k), B(k) complete
            if (k + 1 < 27) {
#pragma unroll
                for (int r = 0; r < MROW; ++r)
                    loadA(idxN[r], &va[r * KK], &vl[r * KKL]);
#pragma unroll
                for (int r = 0; r < MROW; ++r)
                    idxN[r] = (k + 2 < 27) ? nbrIdx(r, k + 2) : NZ;
                __syncthreads();               // drains A(k+1) + B(k+1)
            }
        }
    } else if constexpr (BMODE == 2) {
        // ---- per-k single buffer; 2 barriers/k (covered by co-res block) ----
        int idxN[MROW];
#pragma unroll
        for (int r = 0; r < MROW; ++r)
            loadA(nbrIdx(r, 0), &va[r * KK], &vl[r * KKL]);
#pragma unroll
        for (int r = 0; r < MROW; ++r) idxN[r] = nbrIdx(r, 1);

        for (int k = 0; k < 27; ++k) {
            stageK(k, 0);                      // prev reads done (barrier below)
            __syncthreads();                   // drains stage(k) + A(k)
            mfmaPhase(va, vl, 0);
            if (k + 1 < 27) {
#pragma unroll
                for (int r = 0; r < MROW; ++r)
                    loadA(idxN[r], &va[r * KK], &vl[r * KKL]);
#pragma unroll
                for (int r = 0; r < MROW; ++r)
                    idxN[r] = (k + 2 < 27) ? nbrIdx(r, k + 2) : NZ;
                __syncthreads();               // B(k) reads done before restage
            }
        }
    } else {
        // ---- whole-B resident, no k-loop barriers; PIPEA A reg-dbuf ----
#pragma unroll
        for (int c = w; c < 27 * CH; c += WAVES)
            gld_lds16(Wb + (size_t)c * 512 + lane * 8, &sB[(size_t)c * 512]);
        int idxC = nbrIdx(0, 0);
        loadA(idxC, va, vl);
        int idxN = nbrIdx(0, 1);
        __syncthreads();

        if constexpr (PIPEA) {
            auto body = [&](int k, f16x8* vac, f16x8* vlc, f16x8* van, f16x8* vln) {
                if (k >= 27) return;
                if (k + 1 < 27) {
                    loadA(idxN, van, vln);
                    idxN = (k + 2 < 27) ? nbrIdx(0, k + 2) : NZ;
                }
                mfmaPhase(vac, vlc, k);
            };
            for (int k2 = 0; k2 < 27; k2 += 2) {
                body(k2, va, vl, vaB, vlB);
                body(k2 + 1, vaB, vlB, va, vl);
            }
        } else {
            for (int k = 0; k < 27; ++k) {
                mfmaPhase(va, vl, k);
                if (k + 1 < 27) {
                    loadA(idxN, va, vl);
                    idxN = (k + 2 < 27) ? nbrIdx(0, k + 2) : NZ;
                }
            }
        }
    }

    // ---- epilogue: D col=lane&15, row=(lane>>4)*4+j ----
    const int colg = lane & 15;
    const int rg   = lane >> 4;
#pragma unroll
    for (int r = 0; r < MROW; ++r) {
#pragma unroll
        for (int nt = 0; nt < NTB; ++nt) {
#pragma unroll
            for (int j = 0; j < 4; ++j) {
                float v = acc[r * NTB + nt][j];
                if constexpr (TERMS == 2) v += acc2[r * NTB + nt][j] * (1.f / 4096.f);
                const int n  = n0 + (wrow * MROW + r) * 16 + rg * 4 + j;
                const int co = ((cs * WCO + wco) * NTB + nt) * 16 + colg;
                if (n < Nstore && co < CO_real) {
                    if constexpr (OUTM == 0) {
                        ((float*)outv)[(size_t)n * ostride + ooff + co] = v;
                    } else if constexpr (OUTM == 1) {
                        ((f16*)outv)[(size_t)n * ostride + co] = (f16)v;
                    } else {
                        f16* o = (f16*)outv;
                        const f16 h = (f16)v;
                        o[(size_t)n * ostride + co] = h;
                        o[out_plane + (size_t)n * ostride + co] = (f16)((v - (float)h) * 4096.f);
                    }
                }
            }
        }
    }
}

// nbrm[i] = nbr[i] if that neighbor survives the attention mask, else -1.
// Masked gathers then hit the (L1-resident) zero row instead of pulling
// 384B of zeros through L2/L3 per gather.
__global__ __launch_bounds__(256)
void remap_nbr(const int* __restrict__ nbr, const float* __restrict__ att,
               int* __restrict__ nbrm, size_t total)
{
    const size_t i = (size_t)blockIdx.x * 256 + threadIdx.x;
    if (i >= total) return;
    const int j = nbr[i];
    nbrm[i] = (j >= 0 && att[j] > 0.5f) ? j : -1;
}

// ---------------------------------------------------------------------------
// P-factorized score: P[k][R][c] = f[R] @ Ws[k][:,c] as ONE dense GEMM
// f[N x C] @ Wflat[C x 54->64] (no gather). P is f32 [27][N][2].
// ---------------------------------------------------------------------------
template<int C>
__global__ __launch_bounds__(256)
void pgemm_score(const f16* __restrict__ fin, size_t plane,
                 const f16* __restrict__ Wb,   // (C/32)*4*2 chunks
                 float* __restrict__ P, int N)
{
    constexpr int KK = C / 32;
    constexpr int CH = KK * 4 * 2;
    __shared__ f16 sB[CH * 512];

    const int tid  = threadIdx.x;
    const int lane = tid & 63;
    const int w    = tid >> 6;

    const int n0 = blockIdx.x * 64;
    int site = n0 + w * 16 + (lane & 15);
    if (site > N) site = N;                 // zero row for tails
    const int h8 = (lane >> 4) * 8;

    f16x8 va[KK], vl[KK];
    const f16* arow = fin + (size_t)site * C + h8;
#pragma unroll
    for (int kk = 0; kk < KK; ++kk) {
        va[kk] = *(const f16x8*)(arow + kk * 32);
        vl[kk] = *(const f16x8*)(arow + plane + kk * 32);
    }
    for (int c = w; c < CH; c += 4)
        gld_lds16(Wb + (size_t)c * 512 + lane * 8, &sB[(size_t)c * 512]);

    f32x4 acc[4], acc2[4];
#pragma unroll
    for (int nt = 0; nt < 4; ++nt) {
        acc[nt]  = (f32x4){0.f, 0.f, 0.f, 0.f};
        acc2[nt] = (f32x4){0.f, 0.f, 0.f, 0.f};
    }
    __syncthreads();

#pragma unroll
    for (int kk = 0; kk < KK; ++kk) {
#pragma unroll
        for (int nt = 0; nt < 4; ++nt) {
            const f16* bp = &sB[(size_t)((kk * 4 + nt) * 2) * 512] + lane * 8;
            const f16x8 bh = *(const f16x8*)bp;
            const f16x8 bl = *(const f16x8*)(bp + 512);
            acc[nt]  = __builtin_amdgcn_mfma_f32_16x16x32_f16(va[kk], bh, acc[nt], 0, 0, 0);
            acc2[nt] = __builtin_amdgcn_mfma_f32_16x16x32_f16(va[kk], bl, acc2[nt], 0, 0, 0);
            acc2[nt] = __builtin_amdgcn_mfma_f32_16x16x32_f16(vl[kk], bh, acc2[nt], 0, 0, 0);
        }
    }

    const int colg = lane & 15;
    const int rg   = lane >> 4;
#pragma unroll
    for (int nt = 0; nt < 4; ++nt) {
#pragma unroll
        for (int j = 0; j < 4; ++j) {
            const float r = acc[nt][j] + acc2[nt][j] * (1.f / 4096.f);
            const int n  = n0 + w * 16 + rg * 4 + j;
            const int co = nt * 16 + colg;
            if (n < N && co < 54)
                P[(size_t)(co >> 1) * N * 2 + (size_t)n * 2 + (co & 1)] = r;
        }
    }
}

// score(S) = sum_k P[k][nbr(S,k)]  (f32, k-ordered like the reference);
// also fills the coords columns of ppn.
__global__ __launch_bounds__(256)
void reduce_score(const float* __restrict__ P, const int* __restrict__ nbr,
                  const int* __restrict__ coords, float* __restrict__ ppn, int N)
{
    const int site = blockIdx.x * 256 + threadIdx.x;
    if (site >= N) return;
    float s0 = 0.f, s1 = 0.f;
    const size_t pl = (size_t)N * 2;
#pragma unroll
    for (int k = 0; k < 27; ++k) {
        const int idx = nbr[(size_t)site * 27 + k];
        if (idx >= 0) {
            const float2 p = *(const float2*)(P + (size_t)k * pl + (size_t)idx * 2);
            s0 += p.x; s1 += p.y;
        }
    }
    float* row = ppn + (size_t)site * 6;
    const int* cr = coords + (size_t)site * 4;
    row[0] = (float)cr[0]; row[1] = (float)cr[1];
    row[2] = (float)cr[2]; row[3] = (float)cr[3];
    row[4] = s0; row[5] = s1;
}

// ---------------------------------------------------------------------------
// Pre-pass: f32 rows (optionally x att-mask) -> f16 split planes, plus a
// zero row at index N (gather target for missing neighbors / tail sites).
// ---------------------------------------------------------------------------
template<int TERMS>
__global__ __launch_bounds__(256)
void prepass(const float* __restrict__ f, const float* __restrict__ att,
             f16* __restrict__ dst, size_t plane, int C4, int N)
{
    const size_t i = (size_t)blockIdx.x * 256 + threadIdx.x;
    const size_t total = (size_t)(N + 1) * C4;
    if (i >= total) return;
    const int row = (int)(i / C4);
    float4 v = make_float4(0.f, 0.f, 0.f, 0.f);
    if (row < N) {
        v = *(const float4*)(f + i * 4);
        if (att != nullptr) {
            const float a = att[row];
            v.x *= a; v.y *= a; v.z *= a; v.w *= a;
        }
    }
    const float xs[4] = {v.x, v.y, v.z, v.w};
    f16x4 hi, lo;
#pragma unroll
    for (int j = 0; j < 4; ++j) {
        const f16 h = (f16)xs[j];
        hi[j] = h;
        lo[j] = (f16)((xs[j] - (float)h) * 4096.f);
    }
    *(f16x4*)(dst + i * 4) = hi;
    if constexpr (TERMS == 2)
        *(f16x4*)(dst + plane + i * 4) = lo;
}

// Pack fp32 W[27][C][CO_real] into fragment chunks:
// chunk id = ((((k*CS + cs)*KK + kk)*NTB + nt)*TERMS + term), 512 f16 each.
__global__ __launch_bounds__(256)
void pack_w_f16(const float* __restrict__ W, f16* __restrict__ Wb,
                int C, int CO_real, int CS, int NTB, int TERMS)
{
    const int KK = C / 32;
    const int total = 27 * CS * KK * NTB * TERMS * 64;
    const int t = blockIdx.x * blockDim.x + threadIdx.x;
    if (t >= total) return;
    const int lane = t & 63;
    int cid = t >> 6;
    const int term = cid % TERMS; cid /= TERMS;
    const int nt   = cid % NTB;   cid /= NTB;
    const int kk   = cid % KK;    cid /= KK;
    const int cs   = cid % CS;
    const int k    = cid / CS;
    const int co   = (cs * NTB + nt) * 16 + (lane & 15);
#pragma unroll
    for (int j = 0; j < 8; ++j) {
        const int ci = kk * 32 + (lane >> 4) * 8 + j;
        const float x = (co < CO_real) ? W[((size_t)k * C + ci) * CO_real + co] : 0.f;
        const f16 h = (f16)x;
        Wb[(size_t)t * 8 + j] = (term == 0) ? h : (f16)((x - (float)h) * 4096.f);
    }
}

// Pack score weights [27][C][2] as a flat [C x 54->64] fragment set,
// chunk id = ((kk*4 + nt)*2 + term); flat col co = 2k + c.
__global__ __launch_bounds__(256)
void pack_ws_flat(const float* __restrict__ W, f16* __restrict__ Wb, int C)
{
    const int KK = C / 32;
    const int total = KK * 4 * 2 * 64;
    const int t = blockIdx.x * blockDim.x + threadIdx.x;
    if (t >= total) return;
    const int lane = t & 63;
    int cid = t >> 6;
    const int term = cid % 2;
    const int nt   = (cid >> 1) % 4;
    const int kk   = cid >> 3;
    const int co   = nt * 16 + (lane & 15);
#pragma unroll
    for (int j = 0; j < 8; ++j) {
        const int ci = kk * 32 + (lane >> 4) * 8 + j;
        const float x = (co < 54) ? W[((size_t)(co >> 1) * C + ci) * 2 + (co & 1)] : 0.f;
        const f16 h = (f16)x;
        Wb[(size_t)t * 8 + j] = (term == 0) ? h : (f16)((x - (float)h) * 4096.f);
    }
}

// Pack the fused head [27][32][{3|2|5}->10] directly into fragment chunks
// (chunk per k; single term).
__global__ __launch_bounds__(256)
void pack_wh_frag(const float* __restrict__ wp, const float* __restrict__ ws,
                  const float* __restrict__ wt, f16* __restrict__ Wb)
{
    const int t = blockIdx.x * blockDim.x + threadIdx.x;
    if (t >= 27 * 64) return;
    const int lane = t & 63;
    const int k    = t >> 6;
    const int co   = lane & 15;
#pragma unroll
    for (int j = 0; j < 8; ++j) {
        const int ci = (lane >> 4) * 8 + j;
        float x = 0.f;
        if (co < 3)       x = wp[((size_t)k * 32 + ci) * 3 + co];
        else if (co < 5)  x = ws[((size_t)k * 32 + ci) * 2 + (co - 3)];
        else if (co < 10) x = wt[((size_t)k * 32 + ci) * 5 + (co - 5)];
        Wb[(size_t)t * 8 + j] = (f16)x;
    }
}

__global__ __launch_bounds__(256)
void att_kernel(const float* __restrict__ ppn, const int* __restrict__ parent,
                float* __restrict__ att, int N)
{
    const int i = blockIdx.x * blockDim.x + threadIdx.x;
    if (i >= N) return;
    const int p = parent[i];
    const float s0 = ppn[(size_t)p * 6 + 4];
    const float s1 = ppn[(size_t)p * 6 + 5];
    const float m  = fmaxf(s0, s1);
    const float e0 = expf(s0 - m);
    const float e1 = expf(s1 - m);
    const float p1 = e1 / (e0 + e1);
    att[i] = (p1 > 0.8f) ? 1.f : 0.f;
}

extern "C" void kernel_launch(void* const* d_in, const int* in_sizes, int n_in,
                              void* d_out, int out_size, void* d_ws, size_t ws_size,
                              hipStream_t stream)
{
    const float* f1       = (const float*)d_in[0];
    const float* f2       = (const float*)d_in[1];
    const float* f3       = (const float*)d_in[2];
    const float* w1_conv  = (const float*)d_in[3];
    const float* w1_score = (const float*)d_in[4];
    const float* w2_conv  = (const float*)d_in[5];
    const float* w2_score = (const float*)d_in[6];
    const float* w3_conv  = (const float*)d_in[7];
    const float* w3_pix   = (const float*)d_in[8];
    const float* w3_score = (const float*)d_in[9];
    const float* w3_type  = (const float*)d_in[10];
    const int* coords1    = (const int*)d_in[11];
    const int* coords2    = (const int*)d_in[12];
    const int* nbr1       = (const int*)d_in[13];
    const int* nbr2       = (const int*)d_in[14];
    const int* nbr3       = (const int*)d_in[15];
    const int* parent12   = (const int*)d_in[16];
    const int* parent23   = (const int*)d_in[17];

    const int N1 = in_sizes[0] / 160;   // 20000
    const int N2 = in_sizes[1] / 96;    // 160000
    const int N3 = in_sizes[2] / 32;    // 320000

    // Output layout: points[N3,10] | ppn1[N1,6] | ppn2[N2,6] | att[N2] | att2[N3]
    float* points = (float*)d_out;
    float* ppn1   = points + (size_t)N3 * 10;
    float* ppn2   = ppn1 + (size_t)N1 * 6;
    float* attn   = ppn2 + (size_t)N2 * 6;
    float* attn2  = attn + (size_t)N2;

    // Workspace (all conv inputs have N+1 rows; row N = zeros).
    // Lifetime reuse:
    //   f1s/xs region: f1 split (conv1) -> P1 -> nbr2m (conv2) -> f3s (lvl 3)
    //   f2s region:    f2 split (conv2) -> P2 -> zs + nbr3m  (lvl 3)
    const size_t p1 = (size_t)(N1 + 1) * 160;
    const size_t p2 = (size_t)(N2 + 1) * 96;
    const size_t p3 = (size_t)(N3 + 1) * 32;
    f16* f1s  = (f16*)d_ws;           // 2*p1 = 12.8MB
    f16* xs   = f1s + 2 * p1;         // 2*p1
    f16* f2s  = xs + 2 * p1;          // 2*p2 = 61.4MB
    f16* ys   = f2s + 2 * p2;         // 2*p2
    float* P1 = (float*)f1s;          // 4.3MB  (dead after reduce1)
    int* nbr2m = (int*)f1s;           // N2*27*4 = 17.3MB <= 25.6MB (f1s+xs)
    f16* f3s  = f1s;                  // p3*2B = 20.5MB (after conv2)
    float* P2 = (float*)f2s;          // 34.6MB (dead after reduce2)
    f16* zs   = f2s;                  // 20.5MB
    int* nbr3m = (int*)((char*)f2s + ((p3 * 2 + 255) & ~(size_t)255));
                                      // 34.6MB at +20.5MB, ends 55.1 <= 61.4MB
    f16* Wb1  = ys + 2 * p2;          // 2700 chunks
    f16* Wb2  = Wb1 + (size_t)2700 * 512;   // 972
    f16* Wb3  = Wb2 + (size_t)972 * 512;    // 54
    f16* Wbh  = Wb3 + (size_t)54 * 512;     // 27
    f16* Wsf1 = Wbh + (size_t)27 * 512;     // 40 (score1 flat)
    f16* Wsf2 = Wsf1 + (size_t)40 * 512;    // 24 (score2 flat)

    // ---- weight packing ----
    pack_w_f16<<<(2700 * 64 + 255) / 256, 256, 0, stream>>>(w1_conv, Wb1, 160, 160, 2, 5, 2);
    pack_w_f16<<<(972 * 64 + 255) / 256, 256, 0, stream>>>(w2_conv, Wb2, 96, 96, 2, 3, 2);
    pack_w_f16<<<(54 * 64 + 255) / 256, 256, 0, stream>>>(w3_conv, Wb3, 32, 32, 1, 2, 1);
    pack_wh_frag<<<(27 * 64 + 255) / 256, 256, 0, stream>>>(w3_pix, w3_score, w3_type, Wbh);
    pack_ws_flat<<<(40 * 64 + 255) / 256, 256, 0, stream>>>(w1_score, Wsf1, 160);
    pack_ws_flat<<<(24 * 64 + 255) / 256, 256, 0, stream>>>(w2_score, Wsf2, 96);

    // ---- level 1 ----
    prepass<2><<<(int)(((size_t)(N1 + 1) * 40 + 255) / 256), 256, 0, stream>>>(
        f1, nullptr, f1s, p1, 40, N1);
    // conv1: C=160 NTB=5 CS=2 WCO=1 MROW=1, sbuf (50KB LDS, 2 barriers/k).
    conv_mfma<160, 5, 2, 1, 2, 8, 2, 2, 0, 1><<<160 * 2, 512, 0, stream>>>(
        f1s, p1, nbr1, Wb1, xs, 160, 0, p1, 160, N1, N1 + 1, 160);
    pgemm_score<160><<<(N1 + 63) / 64, 256, 0, stream>>>(xs, p1, Wsf1, P1, N1);
    reduce_score<<<(N1 + 255) / 256, 256, 0, stream>>>(P1, nbr1, coords1, ppn1, N1);
    att_kernel<<<(N2 + 255) / 256, 256, 0, stream>>>(ppn1, parent12, attn, N2);

    // ---- level 2 ----
    // Mask-aware neighbor remap: masked gathers hit the L1-resident zero row.
    // (P1/xs dead here; nbr2m reuses their region. reduce2 still uses nbr2.)
    remap_nbr<<<(int)(((size_t)N2 * 27 + 255) / 256), 256, 0, stream>>>(
        nbr2, attn, nbr2m, (size_t)N2 * 27);
    prepass<2><<<(int)(((size_t)(N2 + 1) * 24 + 255) / 256), 256, 0, stream>>>(
        f2, attn, f2s, p2, 24, N2);
    // conv2: R5/R7 best geometry (NTB=3 CS=2 MROW=1 WAVES=8, 36KB dbuf),
    // with masked-gather remap. tiles=1250 -> pad 1252, nwg=2504 (%8==0).
    conv_mfma<96, 3, 2, 1, 2, 8, 1, 2, 0, 1><<<1252 * 2, 512, 0, stream>>>(
        f2s, p2, nbr2m, Wb2, ys, 96, 0, p2, 96, N2, N2 + 1, 1252);
    pgemm_score<96><<<(N2 + 63) / 64, 256, 0, stream>>>(ys, p2, Wsf2, P2, N2);
    reduce_score<<<(N2 + 255) / 256, 256, 0, stream>>>(P2, nbr2, coords2, ppn2, N2);
    att_kernel<<<(N3 + 255) / 256, 256, 0, stream>>>(ppn2, parent23, attn2, N3);

    // ---- level 3 (points chain, single-term f16) ----
    // nbr3m written after reduce2 (overlaps dead P2 tail, avoids zs).
    remap_nbr<<<(int)(((size_t)N3 * 27 + 255) / 256), 256, 0, stream>>>(
        nbr3, attn2, nbr3m, (size_t)N3 * 27);
    prepass<1><<<(int)(((size_t)(N3 + 1) * 8 + 255) / 256), 256, 0, stream>>>(
        f3, attn2, f3s, 0, 8, N3);
    // conv3: C=32 NTB=2 whole-B (54KB), no k-loop barriers, PIPEA; masked
    // gathers remapped (input f3*att2). tiles=2501 -> pad 2504.
    conv_mfma<32, 2, 1, 1, 1, 8, 0, 1, 1, 1><<<2504, 512, 0, stream>>>(
        f3s, 0, nbr3m, Wb3, zs, 32, 0, 0, 32, N3, N3 + 1, 2504);
    // head: C=32 NTB=1 whole-B (27KB), PIPEA. Input zs is NOT masked ->
    // original nbr3.
    conv_mfma<32, 1, 1, 1, 1, 8, 0, 0, 1, 1><<<2504, 512, 0, stream>>>(
        zs, 0, nbr3, Wbh, points, 10, 0, 0, 10, N3, N3, 2504);
}